// Round 4
// baseline (468.032 us; speedup 1.0000x reference)
//
#include <hip/hip_runtime.h>
#include <hip/hip_bf16.h>
#include <math.h>

// Problem constants (reference: B=64, L=1024, H=64, VOCAB=64)
#define BB 64
#define LL 1024
#define HH 64

typedef float v4f __attribute__((ext_vector_type(4)));

// ---------------------------------------------------------------------------
// Kernel 1: per-token phase.
// block = 256 threads (4 waves), 32 tokens/block, grid = 65536/32 = 2048.
// Computes hn = LN(h + FF(h)), then writes packed stream knv[b][t] =
// [kn(64) | v(64)] (t<1023) plus vthr[b][t] = 0.16*||v||^2 (SQUARED threshold,
// consumed by the scan's sqrt-free gate), or q (t==1023).
// ---------------------------------------------------------------------------
__global__ __launch_bounds__(256, 1)
void token_kernel(const int* __restrict__ seq,
                  const float* __restrict__ embed_W,
                  const float* __restrict__ ff_W1, const float* __restrict__ ff_b1,
                  const float* __restrict__ ff_W2, const float* __restrict__ ff_b2,
                  const float* __restrict__ ln_g, const float* __restrict__ ln_b,
                  const float* __restrict__ kp_W, const float* __restrict__ vp_W,
                  const float* __restrict__ qp_W,
                  float* __restrict__ knv, float* __restrict__ vthr,
                  float* __restrict__ qbuf)
{
    __shared__ __align__(16) float h_s[32][64];    // 8 KB
    __shared__ __align__(16) float t1_s[32][128];  // 16 KB
    __shared__ __align__(16) float hn_s[32][64];   // 8 KB

    const int tid  = threadIdx.x;
    const int tok0 = blockIdx.x * 32;

    // ---- Stage A: embedding gather into LDS ----
#pragma unroll
    for (int k = 0; k < 8; ++k) {
        int e   = k * 256 + tid;
        int tok = e >> 6, i = e & 63;
        int s   = seq[tok0 + tok];
        h_s[tok][i] = embed_W[s * 64 + i];
    }
    __syncthreads();

    // ---- Stage B: FF1 (64 -> 128, ReLU) ----
    {
        const int j = tid & 127;
        const int g = tid >> 7;
        float w1c[64];
#pragma unroll
        for (int ii = 0; ii < 64; ++ii) w1c[ii] = ff_W1[ii * 128 + j];
        const float b1j = ff_b1[j];
#pragma unroll
        for (int tk = 0; tk < 16; ++tk) {
            const int tok = g * 16 + tk;
            const float4* h4 = (const float4*)h_s[tok];
            float a0 = b1j, a1 = 0.f, a2 = 0.f, a3 = 0.f;
#pragma unroll
            for (int w = 0; w < 16; ++w) {
                float4 hv = h4[w];
                a0 = fmaf(hv.x, w1c[4*w+0], a0);
                a1 = fmaf(hv.y, w1c[4*w+1], a1);
                a2 = fmaf(hv.z, w1c[4*w+2], a2);
                a3 = fmaf(hv.w, w1c[4*w+3], a3);
            }
            t1_s[tok][j] = fmaxf((a0 + a1) + (a2 + a3), 0.f);
        }
    }
    __syncthreads();

    // ---- Stage C: FF2 (128 -> 64) + residual + LayerNorm (w2 in 2 halves) ----
    {
        const int i  = tid & 63;
        const int w4 = tid >> 6;
        const float b2i = ff_b2[i];
        const float gi  = ln_g[i];
        const float bi  = ln_b[i];
        float accf[8];
#pragma unroll
        for (int tk = 0; tk < 8; ++tk) accf[tk] = b2i;
#pragma unroll
        for (int h = 0; h < 2; ++h) {
            float w2c[64];
#pragma unroll
            for (int jj = 0; jj < 64; ++jj) w2c[jj] = ff_W2[(h*64 + jj) * 64 + i];
#pragma unroll
            for (int tk = 0; tk < 8; ++tk) {
                const int tok = w4 * 8 + tk;
                const float4* t4 = (const float4*)&t1_s[tok][h*64];
                float a0 = 0.f, a1 = 0.f, a2 = 0.f, a3 = 0.f;
#pragma unroll
                for (int w = 0; w < 16; ++w) {
                    float4 tv = t4[w];
                    a0 = fmaf(tv.x, w2c[4*w+0], a0);
                    a1 = fmaf(tv.y, w2c[4*w+1], a1);
                    a2 = fmaf(tv.z, w2c[4*w+2], a2);
                    a3 = fmaf(tv.w, w2c[4*w+3], a3);
                }
                accf[tk] += (a0 + a1) + (a2 + a3);
            }
        }
#pragma unroll
        for (int tk = 0; tk < 8; ++tk) {
            const int tok = w4 * 8 + tk;
            float x = h_s[tok][i] + accf[tk];
            float s = x;
#pragma unroll
            for (int m = 32; m > 0; m >>= 1) s += __shfl_xor(s, m);
            float mu = s * (1.f / 64.f);
            float d  = x - mu;
            float s2 = d * d;
#pragma unroll
            for (int m = 32; m > 0; m >>= 1) s2 += __shfl_xor(s2, m);
            float var = s2 * (1.f / 64.f);
            hn_s[tok][i] = d / sqrtf(var + 1e-5f) * gi + bi;
        }
    }
    __syncthreads();

    // ---- Stage D: kn/v into packed stream (t<1023) OR q (t==1023) ----
    {
        const int i  = tid & 63;
        const int w4 = tid >> 6;
        float kc[64], vc[64];
#pragma unroll
        for (int ii = 0; ii < 64; ++ii) {
            kc[ii] = kp_W[ii * 64 + i];
            vc[ii] = vp_W[ii * 64 + i];
        }
#pragma unroll
        for (int tk = 0; tk < 8; ++tk) {
            const int tok = w4 * 8 + tk;
            const int tg  = tok0 + tok;
            const int b   = tg >> 10;
            const int t   = tg & 1023;
            const float4* hn4 = (const float4*)hn_s[tok];
            if (t < 1023) {
                float ka0=0.f,ka1=0.f,ka2=0.f,ka3=0.f;
                float va0=0.f,va1=0.f,va2=0.f,va3=0.f;
#pragma unroll
                for (int w = 0; w < 16; ++w) {
                    float4 hv = hn4[w];
                    ka0 = fmaf(hv.x, kc[4*w+0], ka0);
                    ka1 = fmaf(hv.y, kc[4*w+1], ka1);
                    ka2 = fmaf(hv.z, kc[4*w+2], ka2);
                    ka3 = fmaf(hv.w, kc[4*w+3], ka3);
                    va0 = fmaf(hv.x, vc[4*w+0], va0);
                    va1 = fmaf(hv.y, vc[4*w+1], va1);
                    va2 = fmaf(hv.z, vc[4*w+2], va2);
                    va3 = fmaf(hv.w, vc[4*w+3], va3);
                }
                float ka = (ka0 + ka1) + (ka2 + ka3);
                float va = (va0 + va1) + (va2 + va3);
                float kn2 = ka * ka, vn2 = va * va;
#pragma unroll
                for (int m = 32; m > 0; m >>= 1) {
                    kn2 += __shfl_xor(kn2, m);
                    vn2 += __shfl_xor(vn2, m);
                }
                float knorm = fmaxf(sqrtf(kn2), 1e-12f);
                size_t row = ((size_t)b * 1024 + t) * 128;
                knv[row + i]      = ka / knorm;
                knv[row + 64 + i] = va;
                if (i == 0) vthr[b * 1024 + t] = 0.16f * vn2;   // SQUARED threshold
            } else {
                float qa0=0.f,qa1=0.f,qa2=0.f,qa3=0.f;
#pragma unroll
                for (int w = 0; w < 16; ++w) {
                    float4 hv = hn4[w];
                    qa0 = fmaf(hv.x, qp_W[(4*w+0)*64 + i], qa0);
                    qa1 = fmaf(hv.y, qp_W[(4*w+1)*64 + i], qa1);
                    qa2 = fmaf(hv.z, qp_W[(4*w+2)*64 + i], qa2);
                    qa3 = fmaf(hv.w, qp_W[(4*w+3)*64 + i], qa3);
                }
                qbuf[b * 64 + i] = (qa0 + qa1) + (qa2 + qa3);
            }
        }
    }
}

// ---------------------------------------------------------------------------
// Kernel 2: sequential fast-weight scan + output head.
// UPD-TOP / CHAIN / DOT-BOTTOM order (deferred update), 2 fixed kn sets.
//
// Identity: vp_t = M_{t-1} kn_t = (M_{t-2} kn_t) + (kn_{t-1} . kn_t) gd_{t-1}
//
// Iter t (Mreg = M_{t-2} at entry):
//   1. LOADK(X <- kn_{t+1})           [consumed by DOT at the bottom]
//   2. UPD : Mreg += gd_{t-1}*kn_{t-1} (set U)  -> Mreg = M_{t-1}
//   3. LOADK(U <- kn_t)               [anti-dep on the UPD reads; for iter t+1]
//   4. chain: vp_t = fma(c,gd,base); d; e=||d||^2 reduce; gd_t
//   5. gram : c_{t+1} = kn_t . kn_{t+1}
//   6. DOT : base_{t+1} = M_{t-1} . kn_{t+1} (set X)
//
// Both true deps are buffered: UPD(t)->DOT(t) by the chain (~90 insts);
// DOT(t)->UPD(t+1) is an anti-dep (free). The critical cycle is only
// gd -> 1 FMA -> d -> DPP reduce -> gd (~100 cyc). Epilogue applies the
// final update gd_{1022}*kn_{1022} (still in U).
//
// grid = 64 (one block/batch), block = 64 (one wave). Lane i owns M row i.
// kn/v stream staged through LDS via global_load_lds, TRIPLE-buffered 16-step
// chunks; prefetch depth 2 chunks under counted vmcnt(8).
// ---------------------------------------------------------------------------

template<int CTRL>
__device__ __forceinline__ float dppadd(float x) {
    int y = __builtin_amdgcn_update_dpp(0, __float_as_int(x), CTRL, 0xF, 0xF, true);
    return x + __int_as_float(y);
}

// full-wave (64 lane) sum, result broadcast via readlane 63
__device__ __forceinline__ float wave_sum64(float x) {
    x = dppadd<0x111>(x); x = dppadd<0x112>(x);
    x = dppadd<0x114>(x); x = dppadd<0x118>(x);
    x = dppadd<0x142>(x); x = dppadd<0x143>(x);
    return __int_as_float(__builtin_amdgcn_readlane(__float_as_int(x), 63));
}

#define RPT16(F) F(0) F(1) F(2) F(3) F(4) F(5) F(6) F(7) \
                 F(8) F(9) F(10) F(11) F(12) F(13) F(14) F(15)

#define INITM(i) v4f m##i = {0.f, 0.f, 0.f, 0.f};
#define QFMA(i)  accq = __builtin_elementwise_fma(m##i, qq[i], accq);

// load kn row (broadcast b128 reads) into register set P
#define LOADK16(P, NROW) do { \
    const v4f* kk_ = (const v4f*)(NROW); \
    P##0 = kk_[0];  P##1 = kk_[1];  P##2 = kk_[2];  P##3 = kk_[3]; \
    P##4 = kk_[4];  P##5 = kk_[5];  P##6 = kk_[6];  P##7 = kk_[7]; \
    P##8 = kk_[8];  P##9 = kk_[9];  P##10 = kk_[10]; P##11 = kk_[11]; \
    P##12 = kk_[12]; P##13 = kk_[13]; P##14 = kk_[14]; P##15 = kk_[15]; \
} while (0)

// M += gd_s * P   (rank-1, branchless; gd_s==0 is an exact fp no-op)
#define UPD16(P) do { \
    v4f gv_ = {gd_s, gd_s, gd_s, gd_s}; \
    m0  = __builtin_elementwise_fma(gv_, P##0,  m0 ); \
    m1  = __builtin_elementwise_fma(gv_, P##1,  m1 ); \
    m2  = __builtin_elementwise_fma(gv_, P##2,  m2 ); \
    m3  = __builtin_elementwise_fma(gv_, P##3,  m3 ); \
    m4  = __builtin_elementwise_fma(gv_, P##4,  m4 ); \
    m5  = __builtin_elementwise_fma(gv_, P##5,  m5 ); \
    m6  = __builtin_elementwise_fma(gv_, P##6,  m6 ); \
    m7  = __builtin_elementwise_fma(gv_, P##7,  m7 ); \
    m8  = __builtin_elementwise_fma(gv_, P##8,  m8 ); \
    m9  = __builtin_elementwise_fma(gv_, P##9,  m9 ); \
    m10 = __builtin_elementwise_fma(gv_, P##10, m10); \
    m11 = __builtin_elementwise_fma(gv_, P##11, m11); \
    m12 = __builtin_elementwise_fma(gv_, P##12, m12); \
    m13 = __builtin_elementwise_fma(gv_, P##13, m13); \
    m14 = __builtin_elementwise_fma(gv_, P##14, m14); \
    m15 = __builtin_elementwise_fma(gv_, P##15, m15); \
} while (0)

// OUT = (M . P) per lane (in-lane dot, 64 FMA + horizontal)
#define DOT16(P, OUT) do { \
    v4f s0_ = __builtin_elementwise_fma(m0,  P##0, \
              __builtin_elementwise_fma(m4,  P##4, \
              __builtin_elementwise_fma(m8,  P##8,  m12 * P##12))); \
    v4f s1_ = __builtin_elementwise_fma(m1,  P##1, \
              __builtin_elementwise_fma(m5,  P##5, \
              __builtin_elementwise_fma(m9,  P##9,  m13 * P##13))); \
    v4f s2_ = __builtin_elementwise_fma(m2,  P##2, \
              __builtin_elementwise_fma(m6,  P##6, \
              __builtin_elementwise_fma(m10, P##10, m14 * P##14))); \
    v4f s3_ = __builtin_elementwise_fma(m3,  P##3, \
              __builtin_elementwise_fma(m7,  P##7, \
              __builtin_elementwise_fma(m11, P##11, m15 * P##15))); \
    v4f st_ = (s0_ + s1_) + (s2_ + s3_); \
    OUT = (st_.x + st_.y) + (st_.z + st_.w); \
} while (0)

// One iteration t.  A = X set (DOT source), B = U set (UPD source).
//  entry: Mreg = M_{t-2}, B = kn_{t-1}, gd_s = gd_{t-1},
//         base_s = M_{t-2}.kn_t, c_s = kn_{t-1}.kn_t,
//         knl_cur = kn_t[lane], knl_nxt = kn_{t+1}[lane],
//         vv_s = v_t[lane], vv_nxt = v_{t+1}[lane], t2_s/t2_nxt = th2_{t,t+1}.
//  XROW = packed row t+1, UROW = row t, ROW2 = row t+2, TH2P2 = &th2_{t+2}.
#define ITER(XROW, UROW, ROW2, TH2P2) do { \
    LOADK16(A, XROW);                       /* X <- kn_{t+1} */ \
    UPD16(B);                               /* Mreg -> M_{t-1} (gd_{t-1}) */ \
    LOADK16(B, UROW);                       /* U <- kn_t (anti-dep, free) */ \
    float knl2_ = (ROW2)[lane]; \
    float vv2_  = (ROW2)[64 + lane]; \
    float t22_  = *(TH2P2); \
    float vp_ = fmaf(c_s, gd_s, base_s);    /* chain: step t */ \
    float d_  = vv_s - vp_; \
    float e_  = wave_sum64(d_ * d_); \
    gd_s = (e_ > t2_s) ? d_ : 0.0f;         /* gd_t */ \
    float cn_ = wave_sum64(knl_cur * knl_nxt);  /* kn_t.kn_{t+1}, off-chain */ \
    DOT16(A, base_s);                       /* base_{t+1} = M_{t-1}.kn_{t+1} */ \
    c_s = cn_; \
    knl_cur = knl_nxt; knl_nxt = knl2_; \
    vv_s = vv_nxt;     vv_nxt = vv2_; \
    t2_s = t2_nxt;     t2_nxt = t22_; \
} while (0)

// 16 iterations, local steps s=0..15 (t = 16c+s).
// XROW = row s+1 (s=15 -> NB row 0); UROW = row s;
// ROW2 = row s+2 (s=14 -> NB row 0, s=15 -> NB row 1).
#define CHUNK16_D(CB, NB, TP) \
    ITER((CB)+1*128,  (CB)+0*128,  (CB)+2*128,  (TP)+2); \
    ITER((CB)+2*128,  (CB)+1*128,  (CB)+3*128,  (TP)+3); \
    ITER((CB)+3*128,  (CB)+2*128,  (CB)+4*128,  (TP)+4); \
    ITER((CB)+4*128,  (CB)+3*128,  (CB)+5*128,  (TP)+5); \
    ITER((CB)+5*128,  (CB)+4*128,  (CB)+6*128,  (TP)+6); \
    ITER((CB)+6*128,  (CB)+5*128,  (CB)+7*128,  (TP)+7); \
    ITER((CB)+7*128,  (CB)+6*128,  (CB)+8*128,  (TP)+8); \
    ITER((CB)+8*128,  (CB)+7*128,  (CB)+9*128,  (TP)+9); \
    ITER((CB)+9*128,  (CB)+8*128,  (CB)+10*128, (TP)+10); \
    ITER((CB)+10*128, (CB)+9*128,  (CB)+11*128, (TP)+11); \
    ITER((CB)+11*128, (CB)+10*128, (CB)+12*128, (TP)+12); \
    ITER((CB)+12*128, (CB)+11*128, (CB)+13*128, (TP)+13); \
    ITER((CB)+13*128, (CB)+12*128, (CB)+14*128, (TP)+14); \
    ITER((CB)+14*128, (CB)+13*128, (CB)+15*128, (TP)+15); \
    ITER((CB)+15*128, (CB)+14*128, (NB)+0*128,  (TP)+16); \
    ITER((NB)+0*128,  (CB)+15*128, (NB)+1*128,  (TP)+17);

// final 15 iterations: steps t=1008..1022.  Row 1023 (CB row 15) and the NB
// dummy rows feed only lookahead values whose consumers never run.
#define CHUNK15_D(CB, NB, TP) \
    ITER((CB)+1*128,  (CB)+0*128,  (CB)+2*128,  (TP)+2); \
    ITER((CB)+2*128,  (CB)+1*128,  (CB)+3*128,  (TP)+3); \
    ITER((CB)+3*128,  (CB)+2*128,  (CB)+4*128,  (TP)+4); \
    ITER((CB)+4*128,  (CB)+3*128,  (CB)+5*128,  (TP)+5); \
    ITER((CB)+5*128,  (CB)+4*128,  (CB)+6*128,  (TP)+6); \
    ITER((CB)+6*128,  (CB)+5*128,  (CB)+7*128,  (TP)+7); \
    ITER((CB)+7*128,  (CB)+6*128,  (CB)+8*128,  (TP)+8); \
    ITER((CB)+8*128,  (CB)+7*128,  (CB)+9*128,  (TP)+9); \
    ITER((CB)+9*128,  (CB)+8*128,  (CB)+10*128, (TP)+10); \
    ITER((CB)+10*128, (CB)+9*128,  (CB)+11*128, (TP)+11); \
    ITER((CB)+11*128, (CB)+10*128, (CB)+12*128, (TP)+12); \
    ITER((CB)+12*128, (CB)+11*128, (CB)+13*128, (TP)+13); \
    ITER((CB)+13*128, (CB)+12*128, (CB)+14*128, (TP)+14); \
    ITER((CB)+14*128, (CB)+13*128, (CB)+15*128, (TP)+15); \
    ITER((CB)+15*128, (CB)+14*128, (NB)+0*128,  (TP)+16);

// async copy: 1024 B contiguous global -> contiguous LDS (one inst)
__device__ __forceinline__ void gl2lds_1k(const float* g, float* l, int lane) {
    __builtin_amdgcn_global_load_lds(
        (const __attribute__((address_space(1))) void*)(g + lane * 4),
        (__attribute__((address_space(3))) void*)l, 16, 0, 0);
}

__device__ __forceinline__ void prefetch_chunk(const float* g, float* l, int lane) {
#pragma unroll
    for (int w = 0; w < 8; ++w)
        gl2lds_1k(g + w * 256, l + w * 256, lane);
}

__global__ __launch_bounds__(64, 1)
void scan_kernel(const float* __restrict__ knv,
                 const float* __restrict__ vthr,
                 const float* __restrict__ qbuf,
                 const float* __restrict__ rp_W, const float* __restrict__ rp_b,
                 const float* __restrict__ out_W, const float* __restrict__ out_b,
                 float* __restrict__ out)
{
    const int b    = blockIdx.x;
    const int lane = threadIdx.x;
    const float* knvb = knv  + (size_t)b * 1024 * 128;
    const float* thrb = vthr + (size_t)b * 1024;

    __shared__ __align__(16) float thr_s[1040];     // th^2 per step (+pad for peek)
    __shared__ __align__(16) float buf[3 * 2048];   // 3 x 8 KB (16 steps each)
    __shared__ float sh[64];

    RPT16(INITM)

    // two kn register sets with FIXED roles: A = DOT source, B = UPD source
    v4f A0,A1,A2,A3,A4,A5,A6,A7,A8,A9,A10,A11,A12,A13,A14,A15;
    v4f B0,B1,B2,B3,B4,B5,B6,B7,B8,B9,B10,B11,B12,B13,B14,B15;

    // prefetch: thr (4 insts), chunks 0,1,2 (8 each) -> 28 outstanding
#pragma unroll
    for (int w = 0; w < 4; ++w) gl2lds_1k(thrb + w * 256, thr_s + w * 256, lane);
    prefetch_chunk(knvb,        buf,        lane);
    prefetch_chunk(knvb + 2048, buf + 2048, lane);
    prefetch_chunk(knvb + 4096, buf + 4096, lane);

    // thr + chunk 0 resident (chunks 1,2 = 16 loads still in flight)
    asm volatile("s_waitcnt vmcnt(16)" ::: "memory");

    // prologue (t=0): Mreg = M_{-2} = 0, gd_{-1} = 0, base_0 = 0, c_0 = 0.
    // B plays kn_{-1} for the first (gd=0) UPD -> must be finite: zero it.
    {
        v4f z_ = {0.f, 0.f, 0.f, 0.f};
        B0=z_;B1=z_;B2=z_;B3=z_;B4=z_;B5=z_;B6=z_;B7=z_;
        B8=z_;B9=z_;B10=z_;B11=z_;B12=z_;B13=z_;B14=z_;B15=z_;
    }
    float knl_cur = buf[lane];          // kn_0[lane]
    float knl_nxt = buf[128 + lane];    // kn_1[lane]
    float vv_s    = buf[64 + lane];     // v_0[lane]
    float vv_nxt  = buf[192 + lane];    // v_1[lane]
    float t2_s    = thr_s[0];
    float t2_nxt  = thr_s[1];
    float gd_s = 0.f, base_s = 0.f, c_s = 0.f;

#pragma unroll 1
    for (int c = 0; c < 62; ++c) {
        // chunks <= c+1 resident; chunk c+2's 8 loads may be in flight
        asm volatile("s_waitcnt vmcnt(8)" ::: "memory");
        const float* cb = buf + (c % 3) * 2048;
        const float* nb = buf + ((c + 1) % 3) * 2048;
        const float* tp = thr_s + c * 16;
        CHUNK16_D(cb, nb, tp)
        if (c <= 60)
            prefetch_chunk(knvb + (size_t)(c + 3) * 2048,
                           buf + (c % 3) * 2048, lane);
    }
    asm volatile("s_waitcnt vmcnt(0)" ::: "memory");
    {   // chunk 62 (buf[2]), lookahead into chunk 63 (buf[0])
        const float* cb = buf + 2 * 2048;
        const float* nb = buf;
        const float* tp = thr_s + 62 * 16;
        CHUNK16_D(cb, nb, tp)
    }
    {   // chunk 63 (buf[0]): steps 1008..1022; dummy NB = buf[1] (valid LDS)
        const float* cb = buf;
        const float* nb = buf + 2048;
        const float* tp = thr_s + 63 * 16;
        CHUNK15_D(cb, nb, tp)
    }
    // final deferred update: M_{1022} = M_{1021} + gd_{1022} kn_{1022}^T
    // (kn_{1022} is in U: loaded at the last executed ITER's UROW = row 1022)
    UPD16(B);

    // ---- output head: vq = M q ; r = vq @ rp_W + rp_b ; out = r @ out_W + out_b
    const v4f* qq = (const v4f*)(qbuf + b * 64);
    v4f accq = {0.f, 0.f, 0.f, 0.f};
    RPT16(QFMA)
    float vq = (accq.x + accq.y) + (accq.z + accq.w);

    sh[lane] = vq;
    __syncthreads();
    float r = rp_b[lane];
#pragma unroll
    for (int ii = 0; ii < 64; ++ii) r = fmaf(sh[ii], rp_W[ii * 64 + lane], r);
    __syncthreads();
    sh[lane] = r;
    __syncthreads();
    float o = out_b[lane];
#pragma unroll
    for (int ii = 0; ii < 64; ++ii) o = fmaf(sh[ii], out_W[ii * 64 + lane], o);
    out[b * 64 + lane] = o;
}

// ---------------------------------------------------------------------------
// Launch. Workspace (fp32): knv[64][1024][128] (33.55 MB, t=1023 row unused) |
// vthr[64][1024] (262 KB) | qbuf[64][64]. Total ~33.9 MB.
// ---------------------------------------------------------------------------
extern "C" void kernel_launch(void* const* d_in, const int* in_sizes, int n_in,
                              void* d_out, int out_size, void* d_ws, size_t ws_size,
                              hipStream_t stream)
{
    const int*   seq   = (const int*)  d_in[0];
    const float* embed = (const float*)d_in[1];
    const float* ffW1  = (const float*)d_in[2];
    const float* ffb1  = (const float*)d_in[3];
    const float* ffW2  = (const float*)d_in[4];
    const float* ffb2  = (const float*)d_in[5];
    const float* lng   = (const float*)d_in[6];
    const float* lnb   = (const float*)d_in[7];
    const float* kpW   = (const float*)d_in[8];
    const float* vpW   = (const float*)d_in[9];
    const float* qpW   = (const float*)d_in[10];
    const float* rpW   = (const float*)d_in[11];
    const float* rpb   = (const float*)d_in[12];
    const float* outW  = (const float*)d_in[13];
    const float* outb  = (const float*)d_in[14];
    float* out = (float*)d_out;

    float* knv  = (float*)d_ws;
    float* vthr = knv  + (size_t)64 * 1024 * 128;
    float* qbuf = vthr + (size_t)64 * 1024;

    token_kernel<<<2048, 256, 0, stream>>>(seq, embed, ffW1, ffb1, ffW2, ffb2,
                                           lng, lnb, kpW, vpW, qpW,
                                           knv, vthr, qbuf);
    scan_kernel<<<64, 64, 0, stream>>>(knv, vthr, qbuf,
                                       rpW, rpb, outW, outb, out);
}

// Round 5
// 416.992 us; speedup vs baseline: 1.1224x; 1.1224x over previous
//
#include <hip/hip_runtime.h>
#include <hip/hip_bf16.h>
#include <math.h>

// Problem constants (reference: B=64, L=1024, H=64, VOCAB=64)
#define BB 64
#define LL 1024
#define HH 64

typedef float v4f __attribute__((ext_vector_type(4)));
#define F4 __builtin_elementwise_fma

// ---------------------------------------------------------------------------
// Kernel 1: per-token phase (unchanged from round 3).
// ---------------------------------------------------------------------------
__global__ __launch_bounds__(256, 1)
void token_kernel(const int* __restrict__ seq,
                  const float* __restrict__ embed_W,
                  const float* __restrict__ ff_W1, const float* __restrict__ ff_b1,
                  const float* __restrict__ ff_W2, const float* __restrict__ ff_b2,
                  const float* __restrict__ ln_g, const float* __restrict__ ln_b,
                  const float* __restrict__ kp_W, const float* __restrict__ vp_W,
                  const float* __restrict__ qp_W,
                  float* __restrict__ knv, float* __restrict__ vthr,
                  float* __restrict__ qbuf)
{
    __shared__ __align__(16) float h_s[32][64];    // 8 KB
    __shared__ __align__(16) float t1_s[32][128];  // 16 KB
    __shared__ __align__(16) float hn_s[32][64];   // 8 KB

    const int tid  = threadIdx.x;
    const int tok0 = blockIdx.x * 32;

    // ---- Stage A: embedding gather into LDS ----
#pragma unroll
    for (int k = 0; k < 8; ++k) {
        int e   = k * 256 + tid;
        int tok = e >> 6, i = e & 63;
        int s   = seq[tok0 + tok];
        h_s[tok][i] = embed_W[s * 64 + i];
    }
    __syncthreads();

    // ---- Stage B: FF1 (64 -> 128, ReLU) ----
    {
        const int j = tid & 127;
        const int g = tid >> 7;
        float w1c[64];
#pragma unroll
        for (int ii = 0; ii < 64; ++ii) w1c[ii] = ff_W1[ii * 128 + j];
        const float b1j = ff_b1[j];
#pragma unroll
        for (int tk = 0; tk < 16; ++tk) {
            const int tok = g * 16 + tk;
            const float4* h4 = (const float4*)h_s[tok];
            float a0 = b1j, a1 = 0.f, a2 = 0.f, a3 = 0.f;
#pragma unroll
            for (int w = 0; w < 16; ++w) {
                float4 hv = h4[w];
                a0 = fmaf(hv.x, w1c[4*w+0], a0);
                a1 = fmaf(hv.y, w1c[4*w+1], a1);
                a2 = fmaf(hv.z, w1c[4*w+2], a2);
                a3 = fmaf(hv.w, w1c[4*w+3], a3);
            }
            t1_s[tok][j] = fmaxf((a0 + a1) + (a2 + a3), 0.f);
        }
    }
    __syncthreads();

    // ---- Stage C: FF2 (128 -> 64) + residual + LayerNorm ----
    {
        const int i  = tid & 63;
        const int w4 = tid >> 6;
        const float b2i = ff_b2[i];
        const float gi  = ln_g[i];
        const float bi  = ln_b[i];
        float accf[8];
#pragma unroll
        for (int tk = 0; tk < 8; ++tk) accf[tk] = b2i;
#pragma unroll
        for (int h = 0; h < 2; ++h) {
            float w2c[64];
#pragma unroll
            for (int jj = 0; jj < 64; ++jj) w2c[jj] = ff_W2[(h*64 + jj) * 64 + i];
#pragma unroll
            for (int tk = 0; tk < 8; ++tk) {
                const int tok = w4 * 8 + tk;
                const float4* t4 = (const float4*)&t1_s[tok][h*64];
                float a0 = 0.f, a1 = 0.f, a2 = 0.f, a3 = 0.f;
#pragma unroll
                for (int w = 0; w < 16; ++w) {
                    float4 tv = t4[w];
                    a0 = fmaf(tv.x, w2c[4*w+0], a0);
                    a1 = fmaf(tv.y, w2c[4*w+1], a1);
                    a2 = fmaf(tv.z, w2c[4*w+2], a2);
                    a3 = fmaf(tv.w, w2c[4*w+3], a3);
                }
                accf[tk] += (a0 + a1) + (a2 + a3);
            }
        }
#pragma unroll
        for (int tk = 0; tk < 8; ++tk) {
            const int tok = w4 * 8 + tk;
            float x = h_s[tok][i] + accf[tk];
            float s = x;
#pragma unroll
            for (int m = 32; m > 0; m >>= 1) s += __shfl_xor(s, m);
            float mu = s * (1.f / 64.f);
            float d  = x - mu;
            float s2 = d * d;
#pragma unroll
            for (int m = 32; m > 0; m >>= 1) s2 += __shfl_xor(s2, m);
            float var = s2 * (1.f / 64.f);
            hn_s[tok][i] = d / sqrtf(var + 1e-5f) * gi + bi;
        }
    }
    __syncthreads();

    // ---- Stage D: kn/v into packed stream (t<1023) OR q (t==1023) ----
    {
        const int i  = tid & 63;
        const int w4 = tid >> 6;
        float kc[64], vc[64];
#pragma unroll
        for (int ii = 0; ii < 64; ++ii) {
            kc[ii] = kp_W[ii * 64 + i];
            vc[ii] = vp_W[ii * 64 + i];
        }
#pragma unroll
        for (int tk = 0; tk < 8; ++tk) {
            const int tok = w4 * 8 + tk;
            const int tg  = tok0 + tok;
            const int b   = tg >> 10;
            const int t   = tg & 1023;
            const float4* hn4 = (const float4*)hn_s[tok];
            if (t < 1023) {
                float ka0=0.f,ka1=0.f,ka2=0.f,ka3=0.f;
                float va0=0.f,va1=0.f,va2=0.f,va3=0.f;
#pragma unroll
                for (int w = 0; w < 16; ++w) {
                    float4 hv = hn4[w];
                    ka0 = fmaf(hv.x, kc[4*w+0], ka0);
                    ka1 = fmaf(hv.y, kc[4*w+1], ka1);
                    ka2 = fmaf(hv.z, kc[4*w+2], ka2);
                    ka3 = fmaf(hv.w, kc[4*w+3], ka3);
                    va0 = fmaf(hv.x, vc[4*w+0], va0);
                    va1 = fmaf(hv.y, vc[4*w+1], va1);
                    va2 = fmaf(hv.z, vc[4*w+2], va2);
                    va3 = fmaf(hv.w, vc[4*w+3], va3);
                }
                float ka = (ka0 + ka1) + (ka2 + ka3);
                float va = (va0 + va1) + (va2 + va3);
                float kn2 = ka * ka, vn2 = va * va;
#pragma unroll
                for (int m = 32; m > 0; m >>= 1) {
                    kn2 += __shfl_xor(kn2, m);
                    vn2 += __shfl_xor(vn2, m);
                }
                float knorm = fmaxf(sqrtf(kn2), 1e-12f);
                size_t row = ((size_t)b * 1024 + t) * 128;
                knv[row + i]      = ka / knorm;
                knv[row + 64 + i] = va;
                if (i == 0) vthr[b * 1024 + t] = 0.16f * vn2;   // SQUARED threshold
            } else {
                float qa0=0.f,qa1=0.f,qa2=0.f,qa3=0.f;
#pragma unroll
                for (int w = 0; w < 16; ++w) {
                    float4 hv = hn4[w];
                    qa0 = fmaf(hv.x, qp_W[(4*w+0)*64 + i], qa0);
                    qa1 = fmaf(hv.y, qp_W[(4*w+1)*64 + i], qa1);
                    qa2 = fmaf(hv.z, qp_W[(4*w+2)*64 + i], qa2);
                    qa3 = fmaf(hv.w, qp_W[(4*w+3)*64 + i], qa3);
                }
                qbuf[b * 64 + i] = (qa0 + qa1) + (qa2 + qa3);
            }
        }
    }
}

// ---------------------------------------------------------------------------
// Kernel 2: sequential fast-weight scan + output head.
// ROUND-3 SCHEDULE, COLUMN-SPLIT ACROSS 2 WAVES (block = 128 threads).
//
// Wave w owns dot-chains {2w, 2w+1}: v4f column-groups {c, c+4, c+8, c+12}
// for c = 2w and 2w+1. This matches round-3's reduction tree exactly:
//   st = (s0+s1) + (s2+s3)  ==  p_wave0 + p_wave1   (fp add commutes)
// so every gate input is BIT-IDENTICAL to round 3. Per iter each wave does
// half the DOT (32 FMA), half the UPD (32 FMA), half the kn ds_reads; the
// scalar chain (gate + gram) is computed redundantly in both waves from
// full-row scalars. Partial base vectors (v4f per lane) are exchanged one
// step ahead through pex[parity][wave], synced by a raw
// "s_waitcnt lgkmcnt(0); s_barrier" per iter (vmcnt NOT drained -> the
// global_load_lds prefetch pipeline survives the barriers).
//
// grid = 64 (one block/batch), block = 128 (2 waves). Lane i owns M row i;
// wave w owns that row's column-chains 2w,2w+1. Staging: wave w loads rows
// 8w..8w+7 of each 16-row chunk (4 x global_load_lds-16B), counted vmcnt(4).
// ---------------------------------------------------------------------------

template<int CTRL>
__device__ __forceinline__ float dppadd(float x) {
    int y = __builtin_amdgcn_update_dpp(0, __float_as_int(x), CTRL, 0xF, 0xF, true);
    return x + __int_as_float(y);
}

// full-wave (64 lane) sum, result broadcast via readlane 63
__device__ __forceinline__ float wave_sum64(float x) {
    x = dppadd<0x111>(x); x = dppadd<0x112>(x);
    x = dppadd<0x114>(x); x = dppadd<0x118>(x);
    x = dppadd<0x142>(x); x = dppadd<0x143>(x);
    return __int_as_float(__builtin_amdgcn_readlane(__float_as_int(x), 63));
}

// load this wave's half of a kn row into register set P (8 x ds_read_b128)
// chain cA = 2*wid -> float offsets 8*wid + {0,16,32,48}; cB = cA+1 -> +4.
#define LOADK8(P, ROW) do { \
    const float* rA_ = (ROW) + (wid << 3); \
    const float* rB_ = rA_ + 4; \
    P##A0 = *(const v4f*)(rA_ +  0); P##A1 = *(const v4f*)(rA_ + 16); \
    P##A2 = *(const v4f*)(rA_ + 32); P##A3 = *(const v4f*)(rA_ + 48); \
    P##B0 = *(const v4f*)(rB_ +  0); P##B1 = *(const v4f*)(rB_ + 16); \
    P##B2 = *(const v4f*)(rB_ + 32); P##B3 = *(const v4f*)(rB_ + 48); \
} while (0)

// M(half) += gd_s * P(half)   (branchless; gd_s==0 is an exact fp no-op)
#define UPD8(P) do { \
    v4f gv_ = {gd_s, gd_s, gd_s, gd_s}; \
    mA0 = F4(gv_, P##A0, mA0); mA1 = F4(gv_, P##A1, mA1); \
    mA2 = F4(gv_, P##A2, mA2); mA3 = F4(gv_, P##A3, mA3); \
    mB0 = F4(gv_, P##B0, mB0); mB1 = F4(gv_, P##B1, mB1); \
    mB2 = F4(gv_, P##B2, mB2); mB3 = F4(gv_, P##B3, mB3); \
} while (0)

// One iteration t (round-3 ordering, split).  X = kn_{t+1}, Y = kn_t.
//  entry: Mreg(half) = M_{t-1}|half, pown_prev = own partial of base_t,
//         pex[P][1-wid] = other partial of base_t, gd_s = gd_{t-1},
//         c_s = kn_{t-1}.kn_t, scalars as in round 3.
//  exit:  barrier passed; pex[P^1] holds both partials of base_{t+1}.
#define ITER(X, Y, ROW2, TH2P2, P) do { \
    v4f po_ = ((const v4f*)pex[P][1 - wid])[lane];      /* other base_t part */ \
    v4f sA_ = F4(mA0, X##A0, F4(mA1, X##A1, F4(mA2, X##A2, mA3 * X##A3))); \
    v4f sB_ = F4(mB0, X##B0, F4(mB1, X##B1, F4(mB2, X##B2, mB3 * X##B3))); \
    v4f pn_ = sA_ + sB_;                                /* own base_{t+1} part */ \
    float knl2_ = (ROW2)[lane]; \
    float vv2_  = (ROW2)[64 + lane]; \
    float t22_  = *(TH2P2); \
    v4f st_ = pown_prev + po_;                          /* == (s0+s1)+(s2+s3) */ \
    float base_ = (st_.x + st_.y) + (st_.z + st_.w); \
    float vp_ = fmaf(c_s, gd_s, base_); \
    float d_  = vv_s - vp_; \
    float e_  = wave_sum64(d_ * d_); \
    gd_s = (e_ > t2_s) ? d_ : 0.0f;                     /* gd_t */ \
    float cn_ = wave_sum64(knl_cur * knl_nxt); \
    UPD8(Y);                                            /* M -> M_t */ \
    LOADK8(Y, ROW2);                                    /* Y <- kn_{t+2} */ \
    ((v4f*)pex[(P) ^ 1][wid])[lane] = pn_;              /* publish base_{t+1} */ \
    pown_prev = pn_; \
    c_s = cn_; knl_cur = knl_nxt; knl_nxt = knl2_; \
    vv_s = vv_nxt; vv_nxt = vv2_; t2_s = t2_nxt; t2_nxt = t22_; \
    asm volatile("s_waitcnt lgkmcnt(0)\n\ts_barrier" ::: "memory"); \
} while (0)

// 16 iterations, local steps s=0..15 (t = 16c+s); parity = s&1 (16 even).
#define CHUNK16_W(CB, NB, TP) \
    ITER(S,T,(CB)+2*128,(TP)+2,0);   ITER(T,S,(CB)+3*128,(TP)+3,1); \
    ITER(S,T,(CB)+4*128,(TP)+4,0);   ITER(T,S,(CB)+5*128,(TP)+5,1); \
    ITER(S,T,(CB)+6*128,(TP)+6,0);   ITER(T,S,(CB)+7*128,(TP)+7,1); \
    ITER(S,T,(CB)+8*128,(TP)+8,0);   ITER(T,S,(CB)+9*128,(TP)+9,1); \
    ITER(S,T,(CB)+10*128,(TP)+10,0); ITER(T,S,(CB)+11*128,(TP)+11,1); \
    ITER(S,T,(CB)+12*128,(TP)+12,0); ITER(T,S,(CB)+13*128,(TP)+13,1); \
    ITER(S,T,(CB)+14*128,(TP)+14,0); ITER(T,S,(CB)+15*128,(TP)+15,1); \
    ITER(S,T,(NB)+0*128,(TP)+16,0);  ITER(T,S,(NB)+1*128,(TP)+17,1);

// final 15 iterations: steps t=1008..1022 (garbage lookahead rows unused)
#define CHUNK15_W(CB, NB, TP) \
    ITER(S,T,(CB)+2*128,(TP)+2,0);   ITER(T,S,(CB)+3*128,(TP)+3,1); \
    ITER(S,T,(CB)+4*128,(TP)+4,0);   ITER(T,S,(CB)+5*128,(TP)+5,1); \
    ITER(S,T,(CB)+6*128,(TP)+6,0);   ITER(T,S,(CB)+7*128,(TP)+7,1); \
    ITER(S,T,(CB)+8*128,(TP)+8,0);   ITER(T,S,(CB)+9*128,(TP)+9,1); \
    ITER(S,T,(CB)+10*128,(TP)+10,0); ITER(T,S,(CB)+11*128,(TP)+11,1); \
    ITER(S,T,(CB)+12*128,(TP)+12,0); ITER(T,S,(CB)+13*128,(TP)+13,1); \
    ITER(S,T,(CB)+14*128,(TP)+14,0); ITER(T,S,(CB)+15*128,(TP)+15,1); \
    ITER(S,T,(NB)+0*128,(TP)+16,0);

// async copy: 1024 B contiguous global -> contiguous LDS (one inst)
__device__ __forceinline__ void gl2lds_1k(const float* g, float* l, int lane) {
    __builtin_amdgcn_global_load_lds(
        (const __attribute__((address_space(1))) void*)(g + lane * 4),
        (__attribute__((address_space(3))) void*)l, 16, 0, 0);
}

// wave w stages rows 8w..8w+7 of a 16-row chunk (4 KB = 4 insts)
__device__ __forceinline__ void prefetch_half(const float* g, float* l,
                                              int lane, int wid) {
#pragma unroll
    for (int j = 0; j < 4; ++j)
        gl2lds_1k(g + wid * 1024 + j * 256, l + wid * 1024 + j * 256, lane);
}

__global__ __launch_bounds__(128, 1)
void scan_kernel(const float* __restrict__ knv,
                 const float* __restrict__ vthr,
                 const float* __restrict__ qbuf,
                 const float* __restrict__ rp_W, const float* __restrict__ rp_b,
                 const float* __restrict__ out_W, const float* __restrict__ out_b,
                 float* __restrict__ out)
{
    const int b    = blockIdx.x;
    const int tid  = threadIdx.x;
    const int lane = tid & 63;
    const int wid  = tid >> 6;
    const float* knvb = knv  + (size_t)b * 1024 * 128;
    const float* thrb = vthr + (size_t)b * 1024;

    __shared__ __align__(16) float thr_s[1040];      // th^2 per step
    __shared__ __align__(16) float buf[3 * 2048];    // 3 x 8 KB chunks
    __shared__ __align__(16) float pex[2][2][256];   // [parity][wave][lane*4]
    __shared__ float sh[64];

    // M half: chains cA=2*wid (regs mA0..3 = v4f idx cA,cA+4,cA+8,cA+12), cB=cA+1
    v4f mA0={0,0,0,0},mA1={0,0,0,0},mA2={0,0,0,0},mA3={0,0,0,0};
    v4f mB0={0,0,0,0},mB1={0,0,0,0},mB2={0,0,0,0},mB3={0,0,0,0};
    // two kn register half-sets, roles alternate
    v4f SA0,SA1,SA2,SA3,SB0,SB1,SB2,SB3;
    v4f TA0,TA1,TA2,TA3,TB0,TB1,TB2,TB3;

    // staging: wave 0 also loads thr (4 insts); each wave 4 insts/chunk
    if (wid == 0) {
#pragma unroll
        for (int w = 0; w < 4; ++w) gl2lds_1k(thrb + w * 256, thr_s + w * 256, lane);
    }
    prefetch_half(knvb,        buf,        lane, wid);
    prefetch_half(knvb + 2048, buf + 2048, lane, wid);
    prefetch_half(knvb + 4096, buf + 4096, lane, wid);

    // zero pex[0] (both wave slots): 128 threads x 1 v4f = 512 floats
    {
        v4f z_ = {0.f, 0.f, 0.f, 0.f};
        ((v4f*)pex)[tid] = z_;
    }

    // thr + chunks 0,1 resident for own wave (chunk 2 in flight = 4 insts);
    // barrier makes both waves' halves visible.
    asm volatile("s_waitcnt vmcnt(4) lgkmcnt(0)\n\ts_barrier" ::: "memory");

    // prologue (t=0): M=0, gd=0, base_0 = 0 (pex[0]=0, pown_prev=0), c_0=0
    LOADK8(T, buf);            // kn_0 (Y at iter 0)
    LOADK8(S, buf + 128);      // kn_1 (X at iter 0)
    v4f pown_prev = {0.f, 0.f, 0.f, 0.f};
    float knl_cur = buf[lane];
    float knl_nxt = buf[128 + lane];
    float vv_s    = buf[64 + lane];
    float vv_nxt  = buf[192 + lane];
    float t2_s    = thr_s[0];
    float t2_nxt  = thr_s[1];
    float gd_s = 0.f, c_s = 0.f;

#pragma unroll 1
    for (int c = 0; c < 62; ++c) {
        // own outstanding: leftovers of chunk c+1 + chunk c+2's 4 loads.
        // vmcnt(4) -> chunk c+1 (this chunk's NB) resident for own wave;
        // iter-bottom barriers propagate cross-wave.
        asm volatile("s_waitcnt vmcnt(4)" ::: "memory");
        const float* cb = buf + (c % 3) * 2048;
        const float* nb = buf + ((c + 1) % 3) * 2048;
        const float* tp = thr_s + c * 16;
        CHUNK16_W(cb, nb, tp)
        // slot c%3 free for both waves (last iter's lgkm0+barrier drained reads)
        if (c <= 60)
            prefetch_half(knvb + (size_t)(c + 3) * 2048,
                          buf + (c % 3) * 2048, lane, wid);
    }
    asm volatile("s_waitcnt vmcnt(0)" ::: "memory");
    asm volatile("s_barrier" ::: "memory");   // both waves' chunk 62/63 staged
    {   // chunk 62 (buf[2]), lookahead into chunk 63 (buf[0])
        const float* cb = buf + 2 * 2048;
        const float* nb = buf;
        const float* tp = thr_s + 62 * 16;
        CHUNK16_W(cb, nb, tp)
    }
    {   // chunk 63 (buf[0]): steps 1008..1022; dummy NB = buf[1]
        const float* cb = buf;
        const float* nb = buf + 2048;
        const float* tp = thr_s + 63 * 16;
        CHUNK15_W(cb, nb, tp)
    }
    // M final (iter t=1022 applied gd_1022*kn_1022 at its bottom).

    // ---- output head: vq = M q (split + exchange), then wave 0 finishes ----
    {
        const v4f* qq = (const v4f*)(qbuf + b * 64);
        const int w2 = 2 * wid;
        v4f aqA = F4(mA0, qq[w2+0], F4(mA1, qq[w2+4],
                  F4(mA2, qq[w2+8],  mA3 * qq[w2+12])));
        v4f aqB = F4(mB0, qq[w2+1], F4(mB1, qq[w2+5],
                  F4(mB2, qq[w2+9],  mB3 * qq[w2+13])));
        v4f aq = aqA + aqB;
        float vq_own = (aq.x + aq.y) + (aq.z + aq.w);
        ((float*)pex)[wid * 64 + lane] = vq_own;
        asm volatile("s_waitcnt lgkmcnt(0)\n\ts_barrier" ::: "memory");
        float vq = vq_own + ((float*)pex)[(1 - wid) * 64 + lane];

        if (wid == 0) {
            sh[lane] = vq;
            asm volatile("s_waitcnt lgkmcnt(0)" ::: "memory");
            float r = rp_b[lane];
#pragma unroll
            for (int ii = 0; ii < 64; ++ii) r = fmaf(sh[ii], rp_W[ii * 64 + lane], r);
            asm volatile("s_waitcnt lgkmcnt(0)" ::: "memory");
            sh[lane] = r;
            asm volatile("s_waitcnt lgkmcnt(0)" ::: "memory");
            float o = out_b[lane];
#pragma unroll
            for (int ii = 0; ii < 64; ++ii) o = fmaf(sh[ii], out_W[ii * 64 + lane], o);
            out[b * 64 + lane] = o;
        }
    }
}

// ---------------------------------------------------------------------------
// Launch. Workspace (fp32): knv[64][1024][128] (33.55 MB, t=1023 row unused) |
// vthr[64][1024] (262 KB) | qbuf[64][64]. Total ~33.9 MB.
// ---------------------------------------------------------------------------
extern "C" void kernel_launch(void* const* d_in, const int* in_sizes, int n_in,
                              void* d_out, int out_size, void* d_ws, size_t ws_size,
                              hipStream_t stream)
{
    const int*   seq   = (const int*)  d_in[0];
    const float* embed = (const float*)d_in[1];
    const float* ffW1  = (const float*)d_in[2];
    const float* ffb1  = (const float*)d_in[3];
    const float* ffW2  = (const float*)d_in[4];
    const float* ffb2  = (const float*)d_in[5];
    const float* lng   = (const float*)d_in[6];
    const float* lnb   = (const float*)d_in[7];
    const float* kpW   = (const float*)d_in[8];
    const float* vpW   = (const float*)d_in[9];
    const float* qpW   = (const float*)d_in[10];
    const float* rpW   = (const float*)d_in[11];
    const float* rpb   = (const float*)d_in[12];
    const float* outW  = (const float*)d_in[13];
    const float* outb  = (const float*)d_in[14];
    float* out = (float*)d_out;

    float* knv  = (float*)d_ws;
    float* vthr = knv  + (size_t)64 * 1024 * 128;
    float* qbuf = vthr + (size_t)64 * 1024;

    token_kernel<<<2048, 256, 0, stream>>>(seq, embed, ffW1, ffb1, ffW2, ffb2,
                                           lng, lnb, kpW, vpW, qpW,
                                           knv, vthr, qbuf);
    scan_kernel<<<64, 128, 0, stream>>>(knv, vthr, qbuf,
                                        rpW, rpb, outW, outb, out);
}

// Round 6
// 368.650 us; speedup vs baseline: 1.2696x; 1.1311x over previous
//
#include <hip/hip_runtime.h>
#include <hip/hip_bf16.h>
#include <math.h>

// Problem constants (reference: B=64, L=1024, H=64, VOCAB=64)
#define BB 64
#define LL 1024
#define HH 64

typedef float v4f __attribute__((ext_vector_type(4)));
#define F4 __builtin_elementwise_fma

// ---------------------------------------------------------------------------
// Kernel 1: per-token phase (unchanged).
// ---------------------------------------------------------------------------
__global__ __launch_bounds__(256, 1)
void token_kernel(const int* __restrict__ seq,
                  const float* __restrict__ embed_W,
                  const float* __restrict__ ff_W1, const float* __restrict__ ff_b1,
                  const float* __restrict__ ff_W2, const float* __restrict__ ff_b2,
                  const float* __restrict__ ln_g, const float* __restrict__ ln_b,
                  const float* __restrict__ kp_W, const float* __restrict__ vp_W,
                  const float* __restrict__ qp_W,
                  float* __restrict__ knv, float* __restrict__ vthr,
                  float* __restrict__ qbuf)
{
    __shared__ __align__(16) float h_s[32][64];    // 8 KB
    __shared__ __align__(16) float t1_s[32][128];  // 16 KB
    __shared__ __align__(16) float hn_s[32][64];   // 8 KB

    const int tid  = threadIdx.x;
    const int tok0 = blockIdx.x * 32;

    // ---- Stage A: embedding gather into LDS ----
#pragma unroll
    for (int k = 0; k < 8; ++k) {
        int e   = k * 256 + tid;
        int tok = e >> 6, i = e & 63;
        int s   = seq[tok0 + tok];
        h_s[tok][i] = embed_W[s * 64 + i];
    }
    __syncthreads();

    // ---- Stage B: FF1 (64 -> 128, ReLU) ----
    {
        const int j = tid & 127;
        const int g = tid >> 7;
        float w1c[64];
#pragma unroll
        for (int ii = 0; ii < 64; ++ii) w1c[ii] = ff_W1[ii * 128 + j];
        const float b1j = ff_b1[j];
#pragma unroll
        for (int tk = 0; tk < 16; ++tk) {
            const int tok = g * 16 + tk;
            const float4* h4 = (const float4*)h_s[tok];
            float a0 = b1j, a1 = 0.f, a2 = 0.f, a3 = 0.f;
#pragma unroll
            for (int w = 0; w < 16; ++w) {
                float4 hv = h4[w];
                a0 = fmaf(hv.x, w1c[4*w+0], a0);
                a1 = fmaf(hv.y, w1c[4*w+1], a1);
                a2 = fmaf(hv.z, w1c[4*w+2], a2);
                a3 = fmaf(hv.w, w1c[4*w+3], a3);
            }
            t1_s[tok][j] = fmaxf((a0 + a1) + (a2 + a3), 0.f);
        }
    }
    __syncthreads();

    // ---- Stage C: FF2 (128 -> 64) + residual + LayerNorm ----
    {
        const int i  = tid & 63;
        const int w4 = tid >> 6;
        const float b2i = ff_b2[i];
        const float gi  = ln_g[i];
        const float bi  = ln_b[i];
        float accf[8];
#pragma unroll
        for (int tk = 0; tk < 8; ++tk) accf[tk] = b2i;
#pragma unroll
        for (int h = 0; h < 2; ++h) {
            float w2c[64];
#pragma unroll
            for (int jj = 0; jj < 64; ++jj) w2c[jj] = ff_W2[(h*64 + jj) * 64 + i];
#pragma unroll
            for (int tk = 0; tk < 8; ++tk) {
                const int tok = w4 * 8 + tk;
                const float4* t4 = (const float4*)&t1_s[tok][h*64];
                float a0 = 0.f, a1 = 0.f, a2 = 0.f, a3 = 0.f;
#pragma unroll
                for (int w = 0; w < 16; ++w) {
                    float4 tv = t4[w];
                    a0 = fmaf(tv.x, w2c[4*w+0], a0);
                    a1 = fmaf(tv.y, w2c[4*w+1], a1);
                    a2 = fmaf(tv.z, w2c[4*w+2], a2);
                    a3 = fmaf(tv.w, w2c[4*w+3], a3);
                }
                accf[tk] += (a0 + a1) + (a2 + a3);
            }
        }
#pragma unroll
        for (int tk = 0; tk < 8; ++tk) {
            const int tok = w4 * 8 + tk;
            float x = h_s[tok][i] + accf[tk];
            float s = x;
#pragma unroll
            for (int m = 32; m > 0; m >>= 1) s += __shfl_xor(s, m);
            float mu = s * (1.f / 64.f);
            float d  = x - mu;
            float s2 = d * d;
#pragma unroll
            for (int m = 32; m > 0; m >>= 1) s2 += __shfl_xor(s2, m);
            float var = s2 * (1.f / 64.f);
            hn_s[tok][i] = d / sqrtf(var + 1e-5f) * gi + bi;
        }
    }
    __syncthreads();

    // ---- Stage D: kn/v into packed stream (t<1023) OR q (t==1023) ----
    {
        const int i  = tid & 63;
        const int w4 = tid >> 6;
        float kc[64], vc[64];
#pragma unroll
        for (int ii = 0; ii < 64; ++ii) {
            kc[ii] = kp_W[ii * 64 + i];
            vc[ii] = vp_W[ii * 64 + i];
        }
#pragma unroll
        for (int tk = 0; tk < 8; ++tk) {
            const int tok = w4 * 8 + tk;
            const int tg  = tok0 + tok;
            const int b   = tg >> 10;
            const int t   = tg & 1023;
            const float4* hn4 = (const float4*)hn_s[tok];
            if (t < 1023) {
                float ka0=0.f,ka1=0.f,ka2=0.f,ka3=0.f;
                float va0=0.f,va1=0.f,va2=0.f,va3=0.f;
#pragma unroll
                for (int w = 0; w < 16; ++w) {
                    float4 hv = hn4[w];
                    ka0 = fmaf(hv.x, kc[4*w+0], ka0);
                    ka1 = fmaf(hv.y, kc[4*w+1], ka1);
                    ka2 = fmaf(hv.z, kc[4*w+2], ka2);
                    ka3 = fmaf(hv.w, kc[4*w+3], ka3);
                    va0 = fmaf(hv.x, vc[4*w+0], va0);
                    va1 = fmaf(hv.y, vc[4*w+1], va1);
                    va2 = fmaf(hv.z, vc[4*w+2], va2);
                    va3 = fmaf(hv.w, vc[4*w+3], va3);
                }
                float ka = (ka0 + ka1) + (ka2 + ka3);
                float va = (va0 + va1) + (va2 + va3);
                float kn2 = ka * ka, vn2 = va * va;
#pragma unroll
                for (int m = 32; m > 0; m >>= 1) {
                    kn2 += __shfl_xor(kn2, m);
                    vn2 += __shfl_xor(vn2, m);
                }
                float knorm = fmaxf(sqrtf(kn2), 1e-12f);
                size_t row = ((size_t)b * 1024 + t) * 128;
                knv[row + i]      = ka / knorm;
                knv[row + 64 + i] = va;
                if (i == 0) vthr[b * 1024 + t] = 0.16f * vn2;   // SQUARED threshold
            } else {
                float qa0=0.f,qa1=0.f,qa2=0.f,qa3=0.f;
#pragma unroll
                for (int w = 0; w < 16; ++w) {
                    float4 hv = hn4[w];
                    qa0 = fmaf(hv.x, qp_W[(4*w+0)*64 + i], qa0);
                    qa1 = fmaf(hv.y, qp_W[(4*w+1)*64 + i], qa1);
                    qa2 = fmaf(hv.z, qp_W[(4*w+2)*64 + i], qa2);
                    qa3 = fmaf(hv.w, qp_W[(4*w+3)*64 + i], qa3);
                }
                qbuf[b * 64 + i] = (qa0 + qa1) + (qa2 + qa3);
            }
        }
    }
}

// ---------------------------------------------------------------------------
// Kernel 2: sequential fast-weight scan + output head.
// G=2 CHUNKED, 2-WAVE COLUMN SPLIT: one barrier per TWO steps.
//
// Chunk u handles steps (t,t+1) = (2u, 2u+1). Entering: M = M_{2u-3};
// gd_{2u-2}, gd_{2u-1} known (per-lane); sets hold kn_{2u-2..2u+1}.
//   1. UPD(gd_{2u-2}), UPD(gd_{2u-1})        -> M = M_{2u-1}   (off-chain)
//   2. half-DOTs: M_{2u-1}.kn_{2u}, .kn_{2u+1}; fold to 2 scalars/lane
//   3. publish (1 ds_write_b64); lgkmcnt(0); s_barrier
//   4. read other half; stream scalars; LOADK next rows (full chunk of slack)
//   5. 4-way interleaved DPP reduce: S2=|d00|^2, S1=d00.d01, S0=|d01|^2,
//      cnext = kn_{2u+2}.kn_{2u+3}   (all gate-INDEPENDENT)
//   6. chain (scalar): g0 = S2>th0;
//      e1 = S0 - g0*(2*c3*S1 - c3^2*S2)   [exact expansion of |d01-g0*c3*d00|^2]
//      g1 = e1>th1; gd_{2u}=g0?d00:0; gd_{2u+1}=g1?(d01-c3*gd_{2u}):0
// vp_{2u} is EXACT (M current), vp_{2u+1} handled by the expansion -> only
// scalar selects on the gate-serial path. Epilogue applies gd_{1022}.
// Step 1023 is a dummy (garbage row; its gd is discarded, NaN-safe).
//
// grid = 64 (one block/batch), block = 128 (2 waves). Lane i owns M row i;
// wave w owns column-chains 2w,2w+1. Staging identical to round 5.
// ---------------------------------------------------------------------------

template<int CTRL>
__device__ __forceinline__ float dppadd(float x) {
    int y = __builtin_amdgcn_update_dpp(0, __float_as_int(x), CTRL, 0xF, 0xF, true);
    return x + __int_as_float(y);
}

__device__ __forceinline__ float bcast63(float x) {
    return __int_as_float(__builtin_amdgcn_readlane(__float_as_int(x), 63));
}

// full-wave (64 lane) sum, result broadcast (prologue use)
__device__ __forceinline__ float wave_sum64(float x) {
    x = dppadd<0x111>(x); x = dppadd<0x112>(x);
    x = dppadd<0x114>(x); x = dppadd<0x118>(x);
    x = dppadd<0x142>(x); x = dppadd<0x143>(x);
    return bcast63(x);
}

// four independent wave sums, DPP levels interleaved (latency amortized)
__device__ __forceinline__ void wsum4(float& a, float& b, float& c, float& d) {
    a = dppadd<0x111>(a); b = dppadd<0x111>(b); c = dppadd<0x111>(c); d = dppadd<0x111>(d);
    a = dppadd<0x112>(a); b = dppadd<0x112>(b); c = dppadd<0x112>(c); d = dppadd<0x112>(d);
    a = dppadd<0x114>(a); b = dppadd<0x114>(b); c = dppadd<0x114>(c); d = dppadd<0x114>(d);
    a = dppadd<0x118>(a); b = dppadd<0x118>(b); c = dppadd<0x118>(c); d = dppadd<0x118>(d);
    a = dppadd<0x142>(a); b = dppadd<0x142>(b); c = dppadd<0x142>(c); d = dppadd<0x142>(d);
    a = dppadd<0x143>(a); b = dppadd<0x143>(b); c = dppadd<0x143>(c); d = dppadd<0x143>(d);
    a = bcast63(a); b = bcast63(b); c = bcast63(c); d = bcast63(d);
}

// load this wave's half of a kn row into half-set P (8 x ds_read_b128)
#define LOADK8(P, ROW) do { \
    const float* rA_ = (ROW) + (wid << 3); \
    const float* rB_ = rA_ + 4; \
    P##A0 = *(const v4f*)(rA_ +  0); P##A1 = *(const v4f*)(rA_ + 16); \
    P##A2 = *(const v4f*)(rA_ + 32); P##A3 = *(const v4f*)(rA_ + 48); \
    P##B0 = *(const v4f*)(rB_ +  0); P##B1 = *(const v4f*)(rB_ + 16); \
    P##B2 = *(const v4f*)(rB_ + 32); P##B3 = *(const v4f*)(rB_ + 48); \
} while (0)

// M(half) += G * P(half)   (branchless; G==0 is an exact fp no-op)
#define UPD8(P, G) do { \
    v4f gv_ = {G, G, G, G}; \
    mA0 = F4(gv_, P##A0, mA0); mA1 = F4(gv_, P##A1, mA1); \
    mA2 = F4(gv_, P##A2, mA2); mA3 = F4(gv_, P##A3, mA3); \
    mB0 = F4(gv_, P##B0, mB0); mB1 = F4(gv_, P##B1, mB1); \
    mB2 = F4(gv_, P##B2, mB2); mB3 = F4(gv_, P##B3, mB3); \
} while (0)

// One chunk u (steps 2u, 2u+1).  UP,UQ = UPD sources (then refilled from
// ROW2/ROW3 = rows 2u+2, 2u+3); XR,XS = DOT sources (kn_{2u}, kn_{2u+1}).
// Carried scalars: gdp=gd_{2u-2}, gdq=gd_{2u-1} (per-lane), vv0/vv1 =
// v_{2u}/v_{2u+1}[lane], th0/th1, c3 = kn_{2u}.kn_{2u+1}.
#define CHUNK2(UP, UQ, XR, XS, ROW2, ROW3, TH2P, TH3P, PAR) do { \
    UPD8(UP, gdp); \
    UPD8(UQ, gdq); \
    v4f qa_ = F4(mA0, XR##A0, F4(mA1, XR##A1, F4(mA2, XR##A2, mA3 * XR##A3))); \
    v4f qb_ = F4(mB0, XR##B0, F4(mB1, XR##B1, F4(mB2, XR##B2, mB3 * XR##B3))); \
    v4f q0_ = qa_ + qb_; \
    float own0_ = (q0_.x + q0_.y) + (q0_.z + q0_.w); \
    v4f ra_ = F4(mA0, XS##A0, F4(mA1, XS##A1, F4(mA2, XS##A2, mA3 * XS##A3))); \
    v4f rb_ = F4(mB0, XS##B0, F4(mB1, XS##B1, F4(mB2, XS##B2, mB3 * XS##B3))); \
    v4f r0_ = ra_ + rb_; \
    float own1_ = (r0_.x + r0_.y) + (r0_.z + r0_.w); \
    ((float2*)pex[PAR][wid])[lane] = make_float2(own0_, own1_); \
    asm volatile("s_waitcnt lgkmcnt(0)\n\ts_barrier" ::: "memory"); \
    float2 oth_ = ((const float2*)pex[PAR][1 - wid])[lane]; \
    float knl2_ = (ROW2)[lane]; \
    float knl3_ = (ROW3)[lane]; \
    float vv2_  = (ROW2)[64 + lane]; \
    float vv3_  = (ROW3)[64 + lane]; \
    float th2_  = *(TH2P); \
    float th3_  = *(TH3P); \
    LOADK8(UP, ROW2); \
    LOADK8(UQ, ROW3); \
    float base0_ = own0_ + oth_.x; \
    float base1_ = own1_ + oth_.y; \
    float d00_ = vv0 - base0_; \
    float d01_ = vv1 - base1_; \
    float x0_ = d00_ * d00_, x1_ = d00_ * d01_; \
    float x2_ = d01_ * d01_, x3_ = knl2_ * knl3_; \
    wsum4(x0_, x1_, x2_, x3_); \
    bool g0_ = x0_ > th0; \
    float corr_ = fmaf(2.f * c3, x1_, -(c3 * c3) * x0_); \
    float e1_ = g0_ ? (x2_ - corr_) : x2_; \
    bool g1_ = e1_ > th1; \
    float gd0_ = g0_ ? d00_ : 0.f; \
    float d1_  = fmaf(-c3, gd0_, d01_); \
    gdp = gd0_; \
    gdq = g1_ ? d1_ : 0.f; \
    vv0 = vv2_; vv1 = vv3_; th0 = th2_; th1 = th3_; c3 = x3_; \
} while (0)

// 8 chunks covering one 16-row buffer (steps 16c .. 16c+15).
// Even chunks: UPD(U,V), DOT(S,T), load U,V; odd: swapped. Last chunk's
// lookahead rows come from NB.
#define BUF8(CB, NB, TP) \
    CHUNK2(U,V,S,T,(CB)+2*128, (CB)+3*128, (TP)+2, (TP)+3, 0); \
    CHUNK2(S,T,U,V,(CB)+4*128, (CB)+5*128, (TP)+4, (TP)+5, 1); \
    CHUNK2(U,V,S,T,(CB)+6*128, (CB)+7*128, (TP)+6, (TP)+7, 0); \
    CHUNK2(S,T,U,V,(CB)+8*128, (CB)+9*128, (TP)+8, (TP)+9, 1); \
    CHUNK2(U,V,S,T,(CB)+10*128,(CB)+11*128,(TP)+10,(TP)+11,0); \
    CHUNK2(S,T,U,V,(CB)+12*128,(CB)+13*128,(TP)+12,(TP)+13,1); \
    CHUNK2(U,V,S,T,(CB)+14*128,(CB)+15*128,(TP)+14,(TP)+15,0); \
    CHUNK2(S,T,U,V,(NB)+0*128, (NB)+1*128, (TP)+16,(TP)+17,1);

// async copy: 1024 B contiguous global -> contiguous LDS (one inst)
__device__ __forceinline__ void gl2lds_1k(const float* g, float* l, int lane) {
    __builtin_amdgcn_global_load_lds(
        (const __attribute__((address_space(1))) void*)(g + lane * 4),
        (__attribute__((address_space(3))) void*)l, 16, 0, 0);
}

// wave w stages rows 8w..8w+7 of a 16-row buffer (4 KB = 4 insts)
__device__ __forceinline__ void prefetch_half(const float* g, float* l,
                                              int lane, int wid) {
#pragma unroll
    for (int j = 0; j < 4; ++j)
        gl2lds_1k(g + wid * 1024 + j * 256, l + wid * 1024 + j * 256, lane);
}

__global__ __launch_bounds__(128, 1)
void scan_kernel(const float* __restrict__ knv,
                 const float* __restrict__ vthr,
                 const float* __restrict__ qbuf,
                 const float* __restrict__ rp_W, const float* __restrict__ rp_b,
                 const float* __restrict__ out_W, const float* __restrict__ out_b,
                 float* __restrict__ out)
{
    const int b    = blockIdx.x;
    const int tid  = threadIdx.x;
    const int lane = tid & 63;
    const int wid  = tid >> 6;
    const float* knvb = knv  + (size_t)b * 1024 * 128;
    const float* thrb = vthr + (size_t)b * 1024;

    __shared__ __align__(16) float thr_s[1040];      // th^2 per step
    __shared__ __align__(16) float buf[3 * 2048];    // 3 x 8 KB buffers
    __shared__ __align__(16) float pex[2][2][128];   // [parity][wave][lane*2]
    __shared__ float sh[64];

    // M half: chains cA=2*wid (v4f idx cA,cA+4,cA+8,cA+12), cB=cA+1
    v4f mA0={0,0,0,0},mA1={0,0,0,0},mA2={0,0,0,0},mA3={0,0,0,0};
    v4f mB0={0,0,0,0},mB1={0,0,0,0},mB2={0,0,0,0},mB3={0,0,0,0};
    // four kn half-sets; roles alternate per chunk parity
    v4f SA0,SA1,SA2,SA3,SB0,SB1,SB2,SB3;
    v4f TA0,TA1,TA2,TA3,TB0,TB1,TB2,TB3;
    v4f UA0,UA1,UA2,UA3,UB0,UB1,UB2,UB3;
    v4f VA0,VA1,VA2,VA3,VB0,VB1,VB2,VB3;

    // staging: wave 0 also loads thr (4 insts); each wave 4 insts/buffer
    if (wid == 0) {
#pragma unroll
        for (int w = 0; w < 4; ++w) gl2lds_1k(thrb + w * 256, thr_s + w * 256, lane);
    }
    prefetch_half(knvb,        buf,        lane, wid);
    prefetch_half(knvb + 2048, buf + 2048, lane, wid);
    prefetch_half(knvb + 4096, buf + 4096, lane, wid);

    // thr + buffers 0,1 resident for own wave; barrier for cross-wave halves
    asm volatile("s_waitcnt vmcnt(4) lgkmcnt(0)\n\ts_barrier" ::: "memory");

    // prologue: chunk 0 expects S=kn_0, T=kn_1, U=V=kn_{-2,-1}=0 (gd=0 no-op)
    LOADK8(S, buf);
    LOADK8(T, buf + 128);
    {
        v4f z_ = {0.f, 0.f, 0.f, 0.f};
        UA0=z_;UA1=z_;UA2=z_;UA3=z_;UB0=z_;UB1=z_;UB2=z_;UB3=z_;
        VA0=z_;VA1=z_;VA2=z_;VA3=z_;VB0=z_;VB1=z_;VB2=z_;VB3=z_;
    }
    float vv0 = buf[64 + lane];          // v_0[lane]
    float vv1 = buf[192 + lane];         // v_1[lane]
    float th0 = thr_s[0];
    float th1 = thr_s[1];
    float c3  = wave_sum64(buf[lane] * buf[128 + lane]);   // kn_0 . kn_1
    float gdp = 0.f, gdq = 0.f;

#pragma unroll 1
    for (int c = 0; c < 62; ++c) {
        // own outstanding <= 8 (buffers c+1, c+2); vmcnt(4) -> buffer c+1
        // (this iteration's NB) resident; chunk barriers propagate cross-wave.
        asm volatile("s_waitcnt vmcnt(4)" ::: "memory");
        const float* cb = buf + (c % 3) * 2048;
        const float* nb = buf + ((c + 1) % 3) * 2048;
        const float* tp = thr_s + c * 16;
        BUF8(cb, nb, tp)
        if (c <= 60)
            prefetch_half(knvb + (size_t)(c + 3) * 2048,
                          buf + (c % 3) * 2048, lane, wid);
    }
    asm volatile("s_waitcnt vmcnt(0)" ::: "memory");
    asm volatile("s_barrier" ::: "memory");   // both waves' buffers 62,63 staged
    {   // buffer 62 (slot 2), lookahead into buffer 63 (slot 0)
        const float* cb = buf + 2 * 2048;
        const float* nb = buf;
        const float* tp = thr_s + 62 * 16;
        BUF8(cb, nb, tp)
    }
    {   // buffer 63 (slot 0): steps 1008..1023 (1023 = dummy); NB dummy slot 1
        const float* cb = buf;
        const float* nb = buf + 2048;
        const float* tp = thr_s + 63 * 16;
        BUF8(cb, nb, tp)
    }
    // final update: M_{1022} = M_{1021} + gd_{1022} kn_{1022}^T
    // (gdp = gd_{1022}; U holds kn_{1022}, loaded at chunk 510)
    UPD8(U, gdp);

    // ---- output head: vq = M q (split + exchange), then wave 0 finishes ----
    {
        const v4f* qq = (const v4f*)(qbuf + b * 64);
        const int w2 = 2 * wid;
        v4f aqA = F4(mA0, qq[w2+0], F4(mA1, qq[w2+4],
                  F4(mA2, qq[w2+8],  mA3 * qq[w2+12])));
        v4f aqB = F4(mB0, qq[w2+1], F4(mB1, qq[w2+5],
                  F4(mB2, qq[w2+9],  mB3 * qq[w2+13])));
        v4f aq = aqA + aqB;
        float vq_own = (aq.x + aq.y) + (aq.z + aq.w);
        ((float*)pex)[wid * 64 + lane] = vq_own;
        asm volatile("s_waitcnt lgkmcnt(0)\n\ts_barrier" ::: "memory");
        float vq = vq_own + ((float*)pex)[(1 - wid) * 64 + lane];

        if (wid == 0) {
            sh[lane] = vq;
            asm volatile("s_waitcnt lgkmcnt(0)" ::: "memory");
            float r = rp_b[lane];
#pragma unroll
            for (int ii = 0; ii < 64; ++ii) r = fmaf(sh[ii], rp_W[ii * 64 + lane], r);
            asm volatile("s_waitcnt lgkmcnt(0)" ::: "memory");
            sh[lane] = r;
            asm volatile("s_waitcnt lgkmcnt(0)" ::: "memory");
            float o = out_b[lane];
#pragma unroll
            for (int ii = 0; ii < 64; ++ii) o = fmaf(sh[ii], out_W[ii * 64 + lane], o);
            out[b * 64 + lane] = o;
        }
    }
}

// ---------------------------------------------------------------------------
// Launch. Workspace (fp32): knv[64][1024][128] (33.55 MB, t=1023 row unused) |
// vthr[64][1024] (262 KB) | qbuf[64][64]. Total ~33.9 MB.
// ---------------------------------------------------------------------------
extern "C" void kernel_launch(void* const* d_in, const int* in_sizes, int n_in,
                              void* d_out, int out_size, void* d_ws, size_t ws_size,
                              hipStream_t stream)
{
    const int*   seq   = (const int*)  d_in[0];
    const float* embed = (const float*)d_in[1];
    const float* ffW1  = (const float*)d_in[2];
    const float* ffb1  = (const float*)d_in[3];
    const float* ffW2  = (const float*)d_in[4];
    const float* ffb2  = (const float*)d_in[5];
    const float* lng   = (const float*)d_in[6];
    const float* lnb   = (const float*)d_in[7];
    const float* kpW   = (const float*)d_in[8];
    const float* vpW   = (const float*)d_in[9];
    const float* qpW   = (const float*)d_in[10];
    const float* rpW   = (const float*)d_in[11];
    const float* rpb   = (const float*)d_in[12];
    const float* outW  = (const float*)d_in[13];
    const float* outb  = (const float*)d_in[14];
    float* out = (float*)d_out;

    float* knv  = (float*)d_ws;
    float* vthr = knv  + (size_t)64 * 1024 * 128;
    float* qbuf = vthr + (size_t)64 * 1024;

    token_kernel<<<2048, 256, 0, stream>>>(seq, embed, ffW1, ffb1, ffW2, ffb2,
                                           lng, lnb, kpW, vpW, qpW,
                                           knv, vthr, qbuf);
    scan_kernel<<<64, 128, 0, stream>>>(knv, vthr, qbuf,
                                        rpW, rpb, outW, outb, out);
}